// Round 4
// baseline (7990.960 us; speedup 1.0000x reference)
//
#include <hip/hip_runtime.h>
#include <math.h>

// Problem dims
#define Sn 128
#define Bn 16
#define Hn 1024
#define En 512
#define Vn 32000
#define H3 3072
#define NBLK 512   // persistent kernel grid

typedef _Float16 h16;
typedef __attribute__((ext_vector_type(2))) _Float16 h16x2;
typedef __attribute__((ext_vector_type(4))) _Float16 h16x4;
typedef __attribute__((ext_vector_type(8))) _Float16 h16x8;
typedef __attribute__((ext_vector_type(4))) float f32x4;

#if defined(__has_builtin)
#if __has_builtin(__builtin_amdgcn_fdot2)
#define HAS_FDOT2 1
#endif
#endif

__device__ __forceinline__ float dot8(h16x8 a, h16x8 b, float acc) {
#ifdef HAS_FDOT2
  h16x2 a0 = {a[0], a[1]}, b0 = {b[0], b[1]};
  acc = __builtin_amdgcn_fdot2(a0, b0, acc, false);
  h16x2 a1 = {a[2], a[3]}, b1 = {b[2], b[3]};
  acc = __builtin_amdgcn_fdot2(a1, b1, acc, false);
  h16x2 a2 = {a[4], a[5]}, b2 = {b[4], b[5]};
  acc = __builtin_amdgcn_fdot2(a2, b2, acc, false);
  h16x2 a3 = {a[6], a[7]}, b3 = {b[6], b[7]};
  acc = __builtin_amdgcn_fdot2(a3, b3, acc, false);
#else
#pragma unroll
  for (int i = 0; i < 8; ++i) acc = fmaf((float)a[i], (float)b[i], acc);
#endif
  return acc;
}

// ---------- f32 -> fp16 convert ----------
__global__ void cvt_f16_k(const float* __restrict__ src, h16* __restrict__ dst, int n4) {
  int i = blockIdx.x * blockDim.x + threadIdx.x;
  if (i < n4) {
    float4 v = *(const float4*)(src + (size_t)i * 4);
    h16x4 o = { (h16)v.x, (h16)v.y, (h16)v.z, (h16)v.w };
    *(h16x4*)(dst + (size_t)i * 4) = o;
  }
}

// ---------- embedding gather -> fp16 X, time-major rows t = s*Bn + b ----------
__global__ void embed_k(const int* __restrict__ trg, const float* __restrict__ emb,
                        h16* __restrict__ Xh) {
  int t = blockIdx.x;
  int s = t >> 4, b = t & 15;
  int tok = trg[b * Sn + s];
  const float* src = emb + (size_t)tok * En;
  int e = threadIdx.x * 4;
  float4 v = *(const float4*)(src + e);
  h16x4 o = { (h16)v.x, (h16)v.y, (h16)v.z, (h16)v.w };
  *(h16x4*)(Xh + (size_t)t * En + e) = o;
}

// ---------- fp16 MFMA GEMM 128x128: C(M,N) = A(M,K) @ B(N,K)^T + bias ----------
template<int OUT_MODE, bool RELU, bool SWZ>
__global__ __launch_bounds__(256) void gemm_bt(
    const h16* __restrict__ A, const h16* __restrict__ B,
    const float* __restrict__ bias, void* __restrict__ C,
    int M, int N, int K)
{
  __shared__ h16 As[128 * 64];
  __shared__ h16 Bs[128 * 64];
  int tid = threadIdx.x;
  int l = tid & 63, wv = tid >> 6;
  int wr = wv >> 1, wc = wv & 1;

  int work = blockIdx.x;
  if (SWZ) { int q = gridDim.x >> 3; work = (work & 7) * q + (work >> 3); }
  int nMp = M >> 7;
  int brow = (work % nMp) << 7;
  int bcol = (work / nMp) << 7;

  f32x4 acc[4][4];
#pragma unroll
  for (int m = 0; m < 4; ++m)
#pragma unroll
    for (int n = 0; n < 4; ++n) acc[m][n] = (f32x4){0.f, 0.f, 0.f, 0.f};

  int nkt = K >> 6;
  for (int kt = 0; kt < nkt; ++kt) {
    const h16* Ag = A + (size_t)brow * K + kt * 64;
    const h16* Bg = B + (size_t)bcol * K + kt * 64;
#pragma unroll
    for (int c = tid; c < 2048; c += 256) {
      int half = c >> 10;
      int cc = c & 1023;
      int row = cc >> 3, slot = cc & 7;
      const h16* src = (half ? Bg : Ag) + (size_t)row * K + slot * 8;
      uint4 v = *(const uint4*)src;
      h16* dst = (half ? Bs : As) + row * 64 + ((slot ^ (row & 7)) << 3);
      *(uint4*)dst = v;
    }
    __syncthreads();
#pragma unroll
    for (int kk = 0; kk < 2; ++kk) {
      h16x8 af[4], bfr[4];
      int rb = wr * 64 + (l & 15);
      int cb2 = wc * 64 + (l & 15);
      int slot = kk * 4 + (l >> 4);
#pragma unroll
      for (int m = 0; m < 4; ++m) {
        int r = rb + m * 16;
        af[m] = *(const h16x8*)&As[r * 64 + ((slot ^ (r & 7)) << 3)];
      }
#pragma unroll
      for (int n = 0; n < 4; ++n) {
        int r = cb2 + n * 16;
        bfr[n] = *(const h16x8*)&Bs[r * 64 + ((slot ^ (r & 7)) << 3)];
      }
#pragma unroll
      for (int m = 0; m < 4; ++m)
#pragma unroll
        for (int n = 0; n < 4; ++n)
          acc[m][n] = __builtin_amdgcn_mfma_f32_16x16x32_f16(af[m], bfr[n], acc[m][n], 0, 0, 0);
    }
    __syncthreads();
  }

#pragma unroll
  for (int m = 0; m < 4; ++m) {
    int row0 = brow + wr * 64 + m * 16 + ((l >> 4) << 2);
#pragma unroll
    for (int n = 0; n < 4; ++n) {
      int col = bcol + wc * 64 + n * 16 + (l & 15);
      float bv = bias ? bias[col] : 0.f;
#pragma unroll
      for (int i = 0; i < 4; ++i) {
        int row = row0 + i;
        float v = acc[m][n][i] + bv;
        if (RELU) v = fmaxf(v, 0.f);
        if (OUT_MODE == 1) {
          ((h16*)C)[(size_t)row * N + col] = (h16)v;
        } else if (OUT_MODE == 2) {
          int rr = ((row & 15) << 7) + (row >> 4);
          ((float*)C)[(size_t)rr * N + col] = v;
        } else {
          ((float*)C)[(size_t)row * N + col] = v;
        }
      }
    }
  }
}

// ---------- fp16 MFMA GEMM 128Mx256N for the logit projection (OUT_MODE 2 semantics) ----------
__global__ __launch_bounds__(256, 1) void gemm_bt256(
    const h16* __restrict__ A, const h16* __restrict__ B,
    const float* __restrict__ bias, float* __restrict__ C,
    int M, int N, int K)
{
  __shared__ h16 As[128 * 64];
  __shared__ h16 Bs[256 * 64];
  int tid = threadIdx.x;
  int l = tid & 63, wv = tid >> 6;
  int wr = wv >> 1, wc = wv & 1;      // wave tile 64M x 128N

  int work = blockIdx.x;
  int q = gridDim.x >> 3; work = (work & 7) * q + (work >> 3);
  int nMp = M >> 7;
  int brow = (work % nMp) << 7;
  int bcol = (work / nMp) << 8;

  f32x4 acc[4][8];
#pragma unroll
  for (int m = 0; m < 4; ++m)
#pragma unroll
    for (int n = 0; n < 8; ++n) acc[m][n] = (f32x4){0.f, 0.f, 0.f, 0.f};

  int nkt = K >> 6;
  for (int kt = 0; kt < nkt; ++kt) {
    const h16* Ag = A + (size_t)brow * K + kt * 64;
    const h16* Bg = B + (size_t)bcol * K + kt * 64;
#pragma unroll
    for (int c = tid; c < 3072; c += 256) {
      int isB = (c >= 1024);
      int cc = isB ? (c - 1024) : c;
      int row = cc >> 3, slot = cc & 7;
      const h16* src = (isB ? Bg : Ag) + (size_t)row * K + slot * 8;
      uint4 v = *(const uint4*)src;
      h16* dst = (isB ? Bs : As) + row * 64 + ((slot ^ (row & 7)) << 3);
      *(uint4*)dst = v;
    }
    __syncthreads();
#pragma unroll
    for (int kk = 0; kk < 2; ++kk) {
      h16x8 af[4], bfr[8];
      int rb = wr * 64 + (l & 15);
      int cb2 = wc * 128 + (l & 15);
      int slot = kk * 4 + (l >> 4);
#pragma unroll
      for (int m = 0; m < 4; ++m) {
        int r = rb + m * 16;
        af[m] = *(const h16x8*)&As[r * 64 + ((slot ^ (r & 7)) << 3)];
      }
#pragma unroll
      for (int n = 0; n < 8; ++n) {
        int r = cb2 + n * 16;
        bfr[n] = *(const h16x8*)&Bs[r * 64 + ((slot ^ (r & 7)) << 3)];
      }
#pragma unroll
      for (int m = 0; m < 4; ++m)
#pragma unroll
        for (int n = 0; n < 8; ++n)
          acc[m][n] = __builtin_amdgcn_mfma_f32_16x16x32_f16(af[m], bfr[n], acc[m][n], 0, 0, 0);
    }
    __syncthreads();
  }

#pragma unroll
  for (int m = 0; m < 4; ++m) {
    int row0 = brow + wr * 64 + m * 16 + ((l >> 4) << 2);
#pragma unroll
    for (int n = 0; n < 8; ++n) {
      int col = bcol + wc * 128 + n * 16 + (l & 15);
      float bv = bias[col];
#pragma unroll
      for (int i = 0; i < 4; ++i) {
        int row = row0 + i;
        int rr = ((row & 15) << 7) + (row >> 4);   // b*128 + s
        C[(size_t)rr * N + col] = acc[m][n][i] + bv;
      }
    }
  }
}

// ---------- grid barrier (all NBLK blocks co-resident) ----------
__device__ __forceinline__ void gbar(int* __restrict__ root, int tgt) {
  __syncthreads();
  if (threadIdx.x == 0) {
    __threadfence();                         // release: push writes to coherence point
    atomicAdd(root, 1);
    while (__hip_atomic_load(root, __ATOMIC_RELAXED, __HIP_MEMORY_SCOPE_AGENT) < tgt)
      __builtin_amdgcn_s_sleep(4);
    __threadfence();                         // acquire: invalidate stale L1/L2 lines
  }
  __syncthreads();
}

// ---------- persistent GRU recurrence ----------
// Blocks [0,256): layer0, 4 output cols each; [256,512): layer1, 4 output cols each.
// Weights LDS-resident (loaded once). fp16 dot inputs, f32 accumulate (v_dot2_f32_f16),
// fp32 running state for the (1-z)*n + z*h update. One grid barrier per step.
__global__ __launch_bounds__(256, 2) void gru_persist(
    const float* __restrict__ gi0,
    const float* __restrict__ hidden,
    const h16* __restrict__ hinit16,
    const h16* __restrict__ whh0, const float* __restrict__ bhh0,
    const h16* __restrict__ wih1, const float* __restrict__ bih1,
    const h16* __restrict__ whh1, const float* __restrict__ bhh1,
    float* __restrict__ h0f_0, float* __restrict__ h0f_1,
    h16* __restrict__ h0h_0, h16* __restrict__ h0h_1,
    float* __restrict__ h1f_0, float* __restrict__ h1f_1,
    h16* __restrict__ H1A,
    int* __restrict__ flags)
{
  __shared__ h16 ldsw[24 * 1024];            // 48 KB
  int bid = blockIdx.x;
  int tid = threadIdx.x;
  int l = tid & 63, wv = tid >> 6;
  int b = l >> 2, p = l & 3;
  int kb = p << 3;

  if (bid < 256) {
    // -------- layer 0 --------
    int j = (bid << 2) + wv;
#pragma unroll
    for (int it = 0; it < 6; ++it) {
      int e = (it << 11) + (tid << 3);
      int r = e >> 10, k = e & 1023;
      int grow = ((r >> 2) << 10) + (bid << 2) + (r & 3);
      *(uint4*)(ldsw + (r << 10) + k) = *(const uint4*)(whh0 + ((size_t)grow << 10) + k);
    }
    float br = bhh0[j], bz = bhh0[1024 + j], bn = bhh0[2048 + j];
    const h16* Wr = ldsw + ((0 + wv) << 10);
    const h16* Wz = ldsw + ((4 + wv) << 10);
    const h16* Wn = ldsw + ((8 + wv) << 10);
    __syncthreads();

    for (int s = 0; s <= Sn; ++s) {
      if (s) gbar(flags, s << 9);
      if (s < Sn) {
        const h16* hb = ((s == 0) ? hinit16 : ((s & 1) ? h0h_0 : h0h_1)) + (b << 10);
        float ar = 0.f, az = 0.f, an = 0.f;
#pragma unroll 4
        for (int t = 0; t < 32; ++t) {
          int k = kb + (t << 5);
          h16x8 h8 = *(const h16x8*)(hb + k);
          ar = dot8(h8, *(const h16x8*)(Wr + k), ar);
          az = dot8(h8, *(const h16x8*)(Wz + k), az);
          an = dot8(h8, *(const h16x8*)(Wn + k), an);
        }
        ar += __shfl_xor(ar, 1, 64); ar += __shfl_xor(ar, 2, 64);
        az += __shfl_xor(az, 1, 64); az += __shfl_xor(az, 2, 64);
        an += __shfl_xor(an, 1, 64); an += __shfl_xor(an, 2, 64);
        if (p == 0) {
          const float* gi = gi0 + ((size_t)((s << 4) + b) * H3);
          float r = 1.f / (1.f + expf(-(gi[j] + ar + br)));
          float z = 1.f / (1.f + expf(-(gi[1024 + j] + az + bz)));
          float n = tanhf(gi[2048 + j] + r * (an + bn));
          const float* hpf = (s == 0) ? hidden : ((s & 1) ? h0f_0 : h0f_1);
          float out = (1.f - z) * n + z * hpf[(b << 10) + j];
          float* of = (s & 1) ? h0f_1 : h0f_0;
          h16*   oh = (s & 1) ? h0h_1 : h0h_0;
          of[(b << 10) + j] = out;
          oh[(b << 10) + j] = (h16)out;
        }
      }
    }
  } else {
    // -------- layer 1 --------
    int jb = bid - 256;
    int j = (jb << 2) + wv;
#pragma unroll
    for (int it = 0; it < 12; ++it) {
      int e = (it << 11) + (tid << 3);
      int r = e >> 10, k = e & 1023;
      const h16* src = (r < 12) ? wih1 : whh1;
      int rr = (r < 12) ? r : (r - 12);
      int grow = ((rr >> 2) << 10) + (jb << 2) + (rr & 3);
      *(uint4*)(ldsw + (r << 10) + k) = *(const uint4*)(src + ((size_t)grow << 10) + k);
    }
    float bir = bih1[j], biz = bih1[1024 + j], bin = bih1[2048 + j];
    float bhr = bhh1[j], bhz = bhh1[1024 + j], bhn = bhh1[2048 + j];
    const h16* Ur = ldsw + ((0 + wv) << 10);
    const h16* Uz = ldsw + ((4 + wv) << 10);
    const h16* Un = ldsw + ((8 + wv) << 10);
    const h16* Gr = ldsw + ((12 + wv) << 10);
    const h16* Gz = ldsw + ((16 + wv) << 10);
    const h16* Gn = ldsw + ((20 + wv) << 10);
    __syncthreads();

    for (int s = 0; s <= Sn; ++s) {
      if (s) gbar(flags, s << 9);
      if (s >= 1) {
        int sm1 = s - 1;
        const h16* xb = ((s & 1) ? h0h_0 : h0h_1) + (b << 10);   // h0[s-1]
        const h16* hb = ((sm1 == 0) ? (hinit16 + 16384)
                                    : (H1A + ((size_t)(sm1 - 1) << 14))) + (b << 10);
        float air = 0.f, aiz = 0.f, ain = 0.f, ahr = 0.f, ahz = 0.f, ahn = 0.f;
#pragma unroll 2
        for (int t = 0; t < 32; ++t) {
          int k = kb + (t << 5);
          h16x8 x8 = *(const h16x8*)(xb + k);
          h16x8 h8 = *(const h16x8*)(hb + k);
          air = dot8(x8, *(const h16x8*)(Ur + k), air);
          aiz = dot8(x8, *(const h16x8*)(Uz + k), aiz);
          ain = dot8(x8, *(const h16x8*)(Un + k), ain);
          ahr = dot8(h8, *(const h16x8*)(Gr + k), ahr);
          ahz = dot8(h8, *(const h16x8*)(Gz + k), ahz);
          ahn = dot8(h8, *(const h16x8*)(Gn + k), ahn);
        }
        air += __shfl_xor(air, 1, 64); air += __shfl_xor(air, 2, 64);
        aiz += __shfl_xor(aiz, 1, 64); aiz += __shfl_xor(aiz, 2, 64);
        ain += __shfl_xor(ain, 1, 64); ain += __shfl_xor(ain, 2, 64);
        ahr += __shfl_xor(ahr, 1, 64); ahr += __shfl_xor(ahr, 2, 64);
        ahz += __shfl_xor(ahz, 1, 64); ahz += __shfl_xor(ahz, 2, 64);
        ahn += __shfl_xor(ahn, 1, 64); ahn += __shfl_xor(ahn, 2, 64);
        if (p == 0) {
          float r = 1.f / (1.f + expf(-(air + bir + ahr + bhr)));
          float z = 1.f / (1.f + expf(-(aiz + biz + ahz + bhz)));
          float n = tanhf(ain + bin + r * (ahn + bhn));
          const float* hpf = (sm1 == 0) ? (hidden + 16384)
                                        : ((s & 1) ? h1f_1 : h1f_0);
          float out = (1.f - z) * n + z * hpf[(b << 10) + j];
          float* of = (s & 1) ? h1f_0 : h1f_1;
          of[(b << 10) + j] = out;
          H1A[((size_t)sm1 << 14) + (b << 10) + j] = (h16)out;
        }
      }
    }
  }
}

extern "C" void kernel_launch(void* const* d_in, const int* in_sizes, int n_in,
                              void* d_out, int out_size, void* d_ws, size_t ws_size,
                              hipStream_t stream) {
  const float* hidden = (const float*)d_in[0];
  const int*   trg    = (const int*)d_in[1];
  const float* emb    = (const float*)d_in[2];
  const float* w_ih0  = (const float*)d_in[3];
  const float* w_hh0  = (const float*)d_in[4];
  const float* b_ih0  = (const float*)d_in[5];
  const float* b_hh0  = (const float*)d_in[6];
  const float* w_ih1  = (const float*)d_in[7];
  const float* w_hh1  = (const float*)d_in[8];
  const float* b_ih1  = (const float*)d_in[9];
  const float* b_hh1  = (const float*)d_in[10];
  const float* w1     = (const float*)d_in[11];
  const float* b1     = (const float*)d_in[12];
  const float* w2     = (const float*)d_in[13];
  const float* b2     = (const float*)d_in[14];
  const float* b_gen  = (const float*)d_in[15];

  char* ws = (char*)d_ws;
  size_t off = 0;
  float* GI0    = (float*)(ws + off); off += (size_t)Sn * Bn * H3 * 4;      // 25.2 MB
  h16* Xh       = (h16*)(ws + off);   off += (size_t)Sn * Bn * En * 2;
  h16* embH     = (h16*)(ws + off);   off += (size_t)Vn * En * 2;
  h16* wih0H    = (h16*)(ws + off);   off += (size_t)H3 * En * 2;
  h16* w1H      = (h16*)(ws + off);   off += (size_t)Hn * Hn * 2;
  h16* w2H      = (h16*)(ws + off);   off += (size_t)En * Hn * 2;
  h16* whh0H    = (h16*)(ws + off);   off += (size_t)H3 * Hn * 2;
  h16* wih1H    = (h16*)(ws + off);   off += (size_t)H3 * Hn * 2;
  h16* whh1H    = (h16*)(ws + off);   off += (size_t)H3 * Hn * 2;
  h16* H1A      = (h16*)(ws + off);   off += (size_t)Sn * Bn * Hn * 2;
  float* h0f0   = (float*)(ws + off); off += (size_t)Bn * Hn * 4;
  float* h0f1   = (float*)(ws + off); off += (size_t)Bn * Hn * 4;
  float* h1f0   = (float*)(ws + off); off += (size_t)Bn * Hn * 4;
  float* h1f1   = (float*)(ws + off); off += (size_t)Bn * Hn * 4;
  h16* h0h0     = (h16*)(ws + off);   off += (size_t)Bn * Hn * 2;
  h16* h0h1     = (h16*)(ws + off);   off += (size_t)Bn * Hn * 2;
  h16* hinit16  = (h16*)(ws + off);   off += (size_t)2 * Bn * Hn * 2;
  int* flags    = (int*)(ws + off);   off += 256;
  // Tb/Ub alias GI0 (dead after the recurrence)
  h16* Tb = (h16*)GI0;
  h16* Ub = (h16*)((char*)GI0 + (8u << 20));

  // fp16 copies of all operands
  cvt_f16_k<<<16000, 256, 0, stream>>>(emb,   embH,  Vn * En / 4);
  cvt_f16_k<<<1536,  256, 0, stream>>>(w_ih0, wih0H, H3 * En / 4);
  cvt_f16_k<<<1024,  256, 0, stream>>>(w1,    w1H,   Hn * Hn / 4);
  cvt_f16_k<<<512,   256, 0, stream>>>(w2,    w2H,   En * Hn / 4);
  cvt_f16_k<<<3072,  256, 0, stream>>>(w_hh0, whh0H, H3 * Hn / 4);
  cvt_f16_k<<<3072,  256, 0, stream>>>(w_ih1, wih1H, H3 * Hn / 4);
  cvt_f16_k<<<3072,  256, 0, stream>>>(w_hh1, whh1H, H3 * Hn / 4);
  cvt_f16_k<<<32,    256, 0, stream>>>(hidden, hinit16, 2 * Bn * Hn / 4);
  embed_k<<<Sn * Bn, 128, 0, stream>>>(trg, emb, Xh);

  // GI0 = X @ w_ih0^T + b_ih0 (hoisted out of the recurrence)
  gemm_bt<0, false, true><<<384, 256, 0, stream>>>(Xh, wih0H, b_ih0, GI0, Sn * Bn, H3, En);

  // persistent recurrence: 1 launch, 512 co-resident blocks, grid barrier per step
  (void)hipMemsetAsync(flags, 0, 4, stream);
  gru_persist<<<NBLK, 256, 0, stream>>>(GI0, hidden, hinit16,
                                        whh0H, b_hh0, wih1H, b_ih1, whh1H, b_hh1,
                                        h0f0, h0f1, h0h0, h0h1, h1f0, h1f1,
                                        H1A, flags);

  // output head, batched over all 2048 rows
  gemm_bt<1, true,  true><<<128,  256, 0, stream>>>(H1A, w1H, b1, Tb, Sn * Bn, Hn, Hn);
  gemm_bt<1, false, true><<<64,   256, 0, stream>>>(Tb, w2H, b2, Ub, Sn * Bn, En, Hn);
  gemm_bt256<<<2000, 256, 0, stream>>>(Ub, embH, b_gen, (float*)d_out, Sn * Bn, Vn, En);
}

// Round 5
// 1611.565 us; speedup vs baseline: 4.9585x; 4.9585x over previous
//
#include <hip/hip_runtime.h>
#include <math.h>

// Problem dims
#define Sn 128
#define Bn 16
#define Hn 1024
#define En 512
#define Vn 32000
#define H3 3072

typedef _Float16 h16;
typedef __attribute__((ext_vector_type(2))) _Float16 h16x2;
typedef __attribute__((ext_vector_type(4))) _Float16 h16x4;
typedef __attribute__((ext_vector_type(8))) _Float16 h16x8;
typedef __attribute__((ext_vector_type(4))) float f32x4;

#if defined(__has_builtin)
#if __has_builtin(__builtin_amdgcn_fdot2)
#define HAS_FDOT2 1
#endif
#endif

__device__ __forceinline__ float dot8(h16x8 a, h16x8 b, float acc) {
#ifdef HAS_FDOT2
  h16x2 a0 = {a[0], a[1]}, b0 = {b[0], b[1]};
  acc = __builtin_amdgcn_fdot2(a0, b0, acc, false);
  h16x2 a1 = {a[2], a[3]}, b1 = {b[2], b[3]};
  acc = __builtin_amdgcn_fdot2(a1, b1, acc, false);
  h16x2 a2 = {a[4], a[5]}, b2 = {b[4], b[5]};
  acc = __builtin_amdgcn_fdot2(a2, b2, acc, false);
  h16x2 a3 = {a[6], a[7]}, b3 = {b[6], b[7]};
  acc = __builtin_amdgcn_fdot2(a3, b3, acc, false);
#else
#pragma unroll
  for (int i = 0; i < 8; ++i) acc = fmaf((float)a[i], (float)b[i], acc);
#endif
  return acc;
}

// ---------- f32 -> fp16 convert ----------
__global__ void cvt_f16_k(const float* __restrict__ src, h16* __restrict__ dst, int n4) {
  int i = blockIdx.x * blockDim.x + threadIdx.x;
  if (i < n4) {
    float4 v = *(const float4*)(src + (size_t)i * 4);
    h16x4 o = { (h16)v.x, (h16)v.y, (h16)v.z, (h16)v.w };
    *(h16x4*)(dst + (size_t)i * 4) = o;
  }
}

// ---------- embedding gather -> fp16 X, time-major rows t = s*Bn + b ----------
__global__ void embed_k(const int* __restrict__ trg, const float* __restrict__ emb,
                        h16* __restrict__ Xh) {
  int t = blockIdx.x;
  int s = t >> 4, b = t & 15;
  int tok = trg[b * Sn + s];
  const float* src = emb + (size_t)tok * En;
  int e = threadIdx.x * 4;
  float4 v = *(const float4*)(src + e);
  h16x4 o = { (h16)v.x, (h16)v.y, (h16)v.z, (h16)v.w };
  *(h16x4*)(Xh + (size_t)t * En + e) = o;
}

// ---------- fp16 MFMA GEMM 128x128: C(M,N) = A(M,K) @ B(N,K)^T + bias ----------
template<int OUT_MODE, bool RELU, bool SWZ>
__global__ __launch_bounds__(256) void gemm_bt(
    const h16* __restrict__ A, const h16* __restrict__ B,
    const float* __restrict__ bias, void* __restrict__ C,
    int M, int N, int K)
{
  __shared__ h16 As[128 * 64];
  __shared__ h16 Bs[128 * 64];
  int tid = threadIdx.x;
  int l = tid & 63, wv = tid >> 6;
  int wr = wv >> 1, wc = wv & 1;

  int work = blockIdx.x;
  if (SWZ) { int q = gridDim.x >> 3; work = (work & 7) * q + (work >> 3); }
  int nMp = M >> 7;
  int brow = (work % nMp) << 7;
  int bcol = (work / nMp) << 7;

  f32x4 acc[4][4];
#pragma unroll
  for (int m = 0; m < 4; ++m)
#pragma unroll
    for (int n = 0; n < 4; ++n) acc[m][n] = (f32x4){0.f, 0.f, 0.f, 0.f};

  int nkt = K >> 6;
  for (int kt = 0; kt < nkt; ++kt) {
    const h16* Ag = A + (size_t)brow * K + kt * 64;
    const h16* Bg = B + (size_t)bcol * K + kt * 64;
#pragma unroll
    for (int c = tid; c < 2048; c += 256) {
      int half = c >> 10;
      int cc = c & 1023;
      int row = cc >> 3, slot = cc & 7;
      const h16* src = (half ? Bg : Ag) + (size_t)row * K + slot * 8;
      uint4 v = *(const uint4*)src;
      h16* dst = (half ? Bs : As) + row * 64 + ((slot ^ (row & 7)) << 3);
      *(uint4*)dst = v;
    }
    __syncthreads();
#pragma unroll
    for (int kk = 0; kk < 2; ++kk) {
      h16x8 af[4], bfr[4];
      int rb = wr * 64 + (l & 15);
      int cb2 = wc * 64 + (l & 15);
      int slot = kk * 4 + (l >> 4);
#pragma unroll
      for (int m = 0; m < 4; ++m) {
        int r = rb + m * 16;
        af[m] = *(const h16x8*)&As[r * 64 + ((slot ^ (r & 7)) << 3)];
      }
#pragma unroll
      for (int n = 0; n < 4; ++n) {
        int r = cb2 + n * 16;
        bfr[n] = *(const h16x8*)&Bs[r * 64 + ((slot ^ (r & 7)) << 3)];
      }
#pragma unroll
      for (int m = 0; m < 4; ++m)
#pragma unroll
        for (int n = 0; n < 4; ++n)
          acc[m][n] = __builtin_amdgcn_mfma_f32_16x16x32_f16(af[m], bfr[n], acc[m][n], 0, 0, 0);
    }
    __syncthreads();
  }

#pragma unroll
  for (int m = 0; m < 4; ++m) {
    int row0 = brow + wr * 64 + m * 16 + ((l >> 4) << 2);
#pragma unroll
    for (int n = 0; n < 4; ++n) {
      int col = bcol + wc * 64 + n * 16 + (l & 15);
      float bv = bias ? bias[col] : 0.f;
#pragma unroll
      for (int i = 0; i < 4; ++i) {
        int row = row0 + i;
        float v = acc[m][n][i] + bv;
        if (RELU) v = fmaxf(v, 0.f);
        if (OUT_MODE == 1) {
          ((h16*)C)[(size_t)row * N + col] = (h16)v;
        } else if (OUT_MODE == 2) {
          int rr = ((row & 15) << 7) + (row >> 4);
          ((float*)C)[(size_t)rr * N + col] = v;
        } else {
          ((float*)C)[(size_t)row * N + col] = v;
        }
      }
    }
  }
}

// ---------- fp16 MFMA GEMM 128Mx256N for the logit projection ----------
__global__ __launch_bounds__(256, 1) void gemm_bt256(
    const h16* __restrict__ A, const h16* __restrict__ B,
    const float* __restrict__ bias, float* __restrict__ C,
    int M, int N, int K)
{
  __shared__ h16 As[128 * 64];
  __shared__ h16 Bs[256 * 64];
  int tid = threadIdx.x;
  int l = tid & 63, wv = tid >> 6;
  int wr = wv >> 1, wc = wv & 1;

  int work = blockIdx.x;
  int q = gridDim.x >> 3; work = (work & 7) * q + (work >> 3);
  int nMp = M >> 7;
  int brow = (work % nMp) << 7;
  int bcol = (work / nMp) << 8;

  f32x4 acc[4][8];
#pragma unroll
  for (int m = 0; m < 4; ++m)
#pragma unroll
    for (int n = 0; n < 8; ++n) acc[m][n] = (f32x4){0.f, 0.f, 0.f, 0.f};

  int nkt = K >> 6;
  for (int kt = 0; kt < nkt; ++kt) {
    const h16* Ag = A + (size_t)brow * K + kt * 64;
    const h16* Bg = B + (size_t)bcol * K + kt * 64;
#pragma unroll
    for (int c = tid; c < 3072; c += 256) {
      int isB = (c >= 1024);
      int cc = isB ? (c - 1024) : c;
      int row = cc >> 3, slot = cc & 7;
      const h16* src = (isB ? Bg : Ag) + (size_t)row * K + slot * 8;
      uint4 v = *(const uint4*)src;
      h16* dst = (isB ? Bs : As) + row * 64 + ((slot ^ (row & 7)) << 3);
      *(uint4*)dst = v;
    }
    __syncthreads();
#pragma unroll
    for (int kk = 0; kk < 2; ++kk) {
      h16x8 af[4], bfr[8];
      int rb = wr * 64 + (l & 15);
      int cb2 = wc * 128 + (l & 15);
      int slot = kk * 4 + (l >> 4);
#pragma unroll
      for (int m = 0; m < 4; ++m) {
        int r = rb + m * 16;
        af[m] = *(const h16x8*)&As[r * 64 + ((slot ^ (r & 7)) << 3)];
      }
#pragma unroll
      for (int n = 0; n < 8; ++n) {
        int r = cb2 + n * 16;
        bfr[n] = *(const h16x8*)&Bs[r * 64 + ((slot ^ (r & 7)) << 3)];
      }
#pragma unroll
      for (int m = 0; m < 4; ++m)
#pragma unroll
        for (int n = 0; n < 8; ++n)
          acc[m][n] = __builtin_amdgcn_mfma_f32_16x16x32_f16(af[m], bfr[n], acc[m][n], 0, 0, 0);
    }
    __syncthreads();
  }

#pragma unroll
  for (int m = 0; m < 4; ++m) {
    int row0 = brow + wr * 64 + m * 16 + ((l >> 4) << 2);
#pragma unroll
    for (int n = 0; n < 8; ++n) {
      int col = bcol + wc * 128 + n * 16 + (l & 15);
      float bv = bias[col];
#pragma unroll
      for (int i = 0; i < 4; ++i) {
        int row = row0 + i;
        int rr = ((row & 15) << 7) + (row >> 4);   // b*128 + s
        C[(size_t)rr * N + col] = acc[m][n][i] + bv;
      }
    }
  }
}

// ---------- fence-free 2-level grid barrier (256 blocks, 8 groups of 32) ----------
// Preceding __syncthreads drains each wave's vmem (incl. sc1 stores) before arrival.
__device__ __forceinline__ void gbar(int* __restrict__ flags, int n, int bid) {
  __syncthreads();
  if (threadIdx.x == 0) {
    int g = bid >> 5;
    atomicAdd(&flags[g << 5], 1);                    // group counters 128B apart
    if ((bid & 31) == 0) {
      while (__hip_atomic_load(&flags[g << 5], __ATOMIC_RELAXED, __HIP_MEMORY_SCOPE_AGENT) < n * 32)
        __builtin_amdgcn_s_sleep(2);
      atomicAdd(&flags[256], 1);                     // root on its own line
    }
    while (__hip_atomic_load(&flags[256], __ATOMIC_RELAXED, __HIP_MEMORY_SCOPE_AGENT) < n * 8)
      __builtin_amdgcn_s_sleep(2);
    asm volatile("" ::: "memory");                   // no compiler hoisting past the poll
  }
  __syncthreads();
}

// ---------- persistent GRU recurrence, fence-free ----------
// 256 blocks x 768 threads (12 waves), 1 block/CU. Block owns 4 columns of BOTH layers.
// Wave (c*3+role): role 0 = L0 hh-dots + L0 update; 1 = L1 ih-dots; 2 = L1 hh-dots + L1 update.
// fp32 running state lives in registers of the owning lanes. Cross-step fp16 state goes
// through per-step ring buffers: sc1 (agent-scope) stores, plain vectorized reads of
// never-before-cached addresses.
__global__ __launch_bounds__(768, 1) void gru_persist2(
    const float* __restrict__ gi0,
    const float* __restrict__ hidden,
    const h16* __restrict__ hinit16,
    const h16* __restrict__ whh0, const float* __restrict__ bhh0,
    const h16* __restrict__ wih1, const float* __restrict__ bih1,
    const h16* __restrict__ whh1, const float* __restrict__ bhh1,
    h16* __restrict__ h0ring,       // [128][16][1024]
    h16* __restrict__ H1A,          // [128][16][1024]
    int* __restrict__ flags)
{
  extern __shared__ h16 ldsw[];                     // 36 rows x 1024 h16 = 72KB weights
  __shared__ float cmb[4][3][16];                   // L1 ih partials
  __shared__ alignas(8) h16 g0[16][4];              // gather: new h0 (b, c)
  __shared__ alignas(8) h16 g1[16][4];              // gather: new h1 (b, c)

  int bid = blockIdx.x;
  int tid = threadIdx.x;
  int base = bid << 2;

  // one-time replay-staleness guard (L2 inv), before any ring reads
  __threadfence();

  // load this block's weight slice: rows r = c*9+g, g: 0-2 whh0, 3-5 wih1, 6-8 whh1
  for (int i = tid; i < 4608; i += 768) {
    int r = i >> 7, ch = i & 127;
    int c = r / 9, g = r % 9;
    const h16* src = (g < 3) ? whh0 + (((size_t)(g * 1024 + base + c)) << 10)
                   : (g < 6) ? wih1 + (((size_t)((g - 3) * 1024 + base + c)) << 10)
                             : whh1 + (((size_t)((g - 6) * 1024 + base + c)) << 10);
    *(uint4*)(ldsw + r * 1024 + ch * 8) = *(const uint4*)(src + ch * 8);
  }

  int wv = tid >> 6;                 // 0..11
  int l = tid & 63;
  int c = wv / 3, role = wv % 3;
  int j = base + c;
  int b = l >> 2, p = l & 3;
  const h16* wR = ldsw + (c * 9 + role * 3) * 1024;

  float bA = 0, bB = 0, bC = 0, bD = 0, bE = 0, bF = 0;
  if (role == 0) { bA = bhh0[j]; bB = bhh0[1024 + j]; bC = bhh0[2048 + j]; }
  if (role == 2) { bA = bih1[j]; bB = bih1[1024 + j]; bC = bih1[2048 + j];
                   bD = bhh1[j]; bE = bhh1[1024 + j]; bF = bhh1[2048 + j]; }
  float hprev = (role == 0) ? hidden[(b << 10) + j]
              : (role == 2) ? hidden[16384 + (b << 10) + j] : 0.f;
  __syncthreads();

  for (int s = 0; s <= Sn; ++s) {
    bool active = (role == 0) ? (s < Sn) : (s >= 1);
    float a0 = 0.f, a1 = 0.f, a2 = 0.f;
    if (active) {
      const h16* hrow = (role <= 1)
          ? ((s == 0) ? hinit16 : h0ring + (((size_t)(s - 1)) << 14))     // h0[s-1]
          : ((s <= 1) ? hinit16 + 16384 : H1A + (((size_t)(s - 2)) << 14)); // h1[s-2]
      const h16* hb = hrow + (b << 10);
#pragma unroll 4
      for (int t = 0; t < 32; ++t) {
        int k = (p << 3) + (t << 5);
        h16x8 h8 = *(const h16x8*)(hb + k);
        a0 = dot8(h8, *(const h16x8*)(wR + k), a0);
        a1 = dot8(h8, *(const h16x8*)(wR + 1024 + k), a1);
        a2 = dot8(h8, *(const h16x8*)(wR + 2048 + k), a2);
      }
      a0 += __shfl_xor(a0, 1, 64); a0 += __shfl_xor(a0, 2, 64);
      a1 += __shfl_xor(a1, 1, 64); a1 += __shfl_xor(a1, 2, 64);
      a2 += __shfl_xor(a2, 1, 64); a2 += __shfl_xor(a2, 2, 64);
      if (role == 1 && p == 0) { cmb[c][0][b] = a0; cmb[c][1][b] = a1; cmb[c][2][b] = a2; }
    }
    __syncthreads();   // [A] L1 ih partials visible
    if (active && p == 0) {
      if (role == 0) {
        const float* gi = gi0 + (size_t)((s << 4) + b) * H3;
        float r = 1.f / (1.f + expf(-(gi[j] + a0 + bA)));
        float z = 1.f / (1.f + expf(-(gi[1024 + j] + a1 + bB)));
        float n = tanhf(gi[2048 + j] + r * (a2 + bC));
        float out = (1.f - z) * n + z * hprev;
        hprev = out;
        g0[b][c] = (h16)out;
      } else if (role == 2) {
        float air = cmb[c][0][b], aiz = cmb[c][1][b], ain = cmb[c][2][b];
        float r = 1.f / (1.f + expf(-(air + bA + a0 + bD)));
        float z = 1.f / (1.f + expf(-(aiz + bB + a1 + bE)));
        float n = tanhf(ain + bC + r * (a2 + bF));
        float out = (1.f - z) * n + z * hprev;
        hprev = out;
        g1[b][c] = (h16)out;
      }
    }
    __syncthreads();   // [B] gather buffers complete
    if (wv == 0 && l < 16 && s < Sn) {
      unsigned long long v = *(const unsigned long long*)&g0[l][0];
      __hip_atomic_store((unsigned long long*)(h0ring + (((size_t)s) << 14) + (l << 10) + base),
                         v, __ATOMIC_RELAXED, __HIP_MEMORY_SCOPE_AGENT);
    }
    if (wv == 3 && l < 16 && s >= 1) {
      unsigned long long v = *(const unsigned long long*)&g1[l][0];
      __hip_atomic_store((unsigned long long*)(H1A + (((size_t)(s - 1)) << 14) + (l << 10) + base),
                         v, __ATOMIC_RELAXED, __HIP_MEMORY_SCOPE_AGENT);
    }
    if (s < Sn) gbar(flags, s + 1, bid);
  }
}

extern "C" void kernel_launch(void* const* d_in, const int* in_sizes, int n_in,
                              void* d_out, int out_size, void* d_ws, size_t ws_size,
                              hipStream_t stream) {
  const float* hidden = (const float*)d_in[0];
  const int*   trg    = (const int*)d_in[1];
  const float* emb    = (const float*)d_in[2];
  const float* w_ih0  = (const float*)d_in[3];
  const float* w_hh0  = (const float*)d_in[4];
  const float* b_ih0  = (const float*)d_in[5];
  const float* b_hh0  = (const float*)d_in[6];
  const float* w_ih1  = (const float*)d_in[7];
  const float* w_hh1  = (const float*)d_in[8];
  const float* b_ih1  = (const float*)d_in[9];
  const float* b_hh1  = (const float*)d_in[10];
  const float* w1     = (const float*)d_in[11];
  const float* b1     = (const float*)d_in[12];
  const float* w2     = (const float*)d_in[13];
  const float* b2     = (const float*)d_in[14];
  const float* b_gen  = (const float*)d_in[15];

  char* ws = (char*)d_ws;
  size_t off = 0;
  float* GI0    = (float*)(ws + off); off += (size_t)Sn * Bn * H3 * 4;      // 25.2 MB
  h16* Xh       = (h16*)(ws + off);   off += (size_t)Sn * Bn * En * 2;
  h16* embH     = (h16*)(ws + off);   off += (size_t)Vn * En * 2;
  h16* wih0H    = (h16*)(ws + off);   off += (size_t)H3 * En * 2;
  h16* w1H      = (h16*)(ws + off);   off += (size_t)Hn * Hn * 2;
  h16* w2H      = (h16*)(ws + off);   off += (size_t)En * Hn * 2;
  h16* whh0H    = (h16*)(ws + off);   off += (size_t)H3 * Hn * 2;
  h16* wih1H    = (h16*)(ws + off);   off += (size_t)H3 * Hn * 2;
  h16* whh1H    = (h16*)(ws + off);   off += (size_t)H3 * Hn * 2;
  h16* H1A      = (h16*)(ws + off);   off += (size_t)Sn * Bn * Hn * 2;      // 4.2 MB
  h16* h0ring   = (h16*)(ws + off);   off += (size_t)Sn * Bn * Hn * 2;      // 4.2 MB
  h16* hinit16  = (h16*)(ws + off);   off += (size_t)2 * Bn * Hn * 2;
  int* flags    = (int*)(ws + off);   off += 2048;
  // Tb/Ub alias GI0 (dead after the recurrence)
  h16* Tb = (h16*)GI0;
  h16* Ub = (h16*)((char*)GI0 + (8u << 20));

  // fp16 copies of all operands
  cvt_f16_k<<<16000, 256, 0, stream>>>(emb,   embH,  Vn * En / 4);
  cvt_f16_k<<<1536,  256, 0, stream>>>(w_ih0, wih0H, H3 * En / 4);
  cvt_f16_k<<<1024,  256, 0, stream>>>(w1,    w1H,   Hn * Hn / 4);
  cvt_f16_k<<<512,   256, 0, stream>>>(w2,    w2H,   En * Hn / 4);
  cvt_f16_k<<<3072,  256, 0, stream>>>(w_hh0, whh0H, H3 * Hn / 4);
  cvt_f16_k<<<3072,  256, 0, stream>>>(w_ih1, wih1H, H3 * Hn / 4);
  cvt_f16_k<<<3072,  256, 0, stream>>>(w_hh1, whh1H, H3 * Hn / 4);
  cvt_f16_k<<<32,    256, 0, stream>>>(hidden, hinit16, 2 * Bn * Hn / 4);
  embed_k<<<Sn * Bn, 128, 0, stream>>>(trg, emb, Xh);

  // GI0 = X @ w_ih0^T + b_ih0 (hoisted out of the recurrence)
  gemm_bt<0, false, true><<<384, 256, 0, stream>>>(Xh, wih0H, b_ih0, GI0, Sn * Bn, H3, En);

  // persistent recurrence: 256 blocks (1/CU), fence-free tree barrier per step
  (void)hipMemsetAsync(flags, 0, 2048, stream);
  const int LDSZ = 36 * 1024 * 2;   // 72KB dynamic
  (void)hipFuncSetAttribute(reinterpret_cast<const void*>(gru_persist2),
                            hipFuncAttributeMaxDynamicSharedMemorySize, LDSZ);
  gru_persist2<<<256, 768, LDSZ, stream>>>(GI0, hidden, hinit16,
                                           whh0H, b_hh0, wih1H, b_ih1, whh1H, b_hh1,
                                           h0ring, H1A, flags);

  // output head, batched over all 2048 rows
  gemm_bt<1, true,  true><<<128,  256, 0, stream>>>(H1A, w1H, b1, Tb, Sn * Bn, Hn, Hn);
  gemm_bt<1, false, true><<<64,   256, 0, stream>>>(Tb, w2H, b2, Ub, Sn * Bn, En, Hn);
  gemm_bt256<<<2000, 256, 0, stream>>>(Ub, embH, b_gen, (float*)d_out, Sn * Bn, Vn, En);
}

// Round 6
// 1483.695 us; speedup vs baseline: 5.3858x; 1.0862x over previous
//
#include <hip/hip_runtime.h>
#include <math.h>

// Problem dims
#define Sn 128
#define Bn 16
#define Hn 1024
#define En 512
#define Vn 32000
#define H3 3072

typedef _Float16 h16;
typedef __attribute__((ext_vector_type(2))) _Float16 h16x2;
typedef __attribute__((ext_vector_type(4))) _Float16 h16x4;
typedef __attribute__((ext_vector_type(8))) _Float16 h16x8;
typedef __attribute__((ext_vector_type(4))) float f32x4;

#if defined(__has_builtin)
#if __has_builtin(__builtin_amdgcn_fdot2)
#define HAS_FDOT2 1
#endif
#endif

__device__ __forceinline__ float dot8(h16x8 a, h16x8 b, float acc) {
#ifdef HAS_FDOT2
  h16x2 a0 = {a[0], a[1]}, b0 = {b[0], b[1]};
  acc = __builtin_amdgcn_fdot2(a0, b0, acc, false);
  h16x2 a1 = {a[2], a[3]}, b1 = {b[2], b[3]};
  acc = __builtin_amdgcn_fdot2(a1, b1, acc, false);
  h16x2 a2 = {a[4], a[5]}, b2 = {b[4], b[5]};
  acc = __builtin_amdgcn_fdot2(a2, b2, acc, false);
  h16x2 a3 = {a[6], a[7]}, b3 = {b[6], b[7]};
  acc = __builtin_amdgcn_fdot2(a3, b3, acc, false);
#else
#pragma unroll
  for (int i = 0; i < 8; ++i) acc = fmaf((float)a[i], (float)b[i], acc);
#endif
  return acc;
}

// ---------- fused f32 -> fp16 convert for ALL operands (one launch) ----------
// segment boundaries in float4-quads (compile-time)
#define Q_EMB   4096000
#define Q_WIH0  (Q_EMB + 393216)
#define Q_W1    (Q_WIH0 + 262144)
#define Q_W2    (Q_W1 + 131072)
#define Q_WHH0  (Q_W2 + 786432)
#define Q_WIH1  (Q_WHH0 + 786432)
#define Q_WHH1  (Q_WIH1 + 786432)
#define Q_HID   (Q_WHH1 + 8192)
__global__ __launch_bounds__(256) void cvt_all_k(
    const float* __restrict__ emb, const float* __restrict__ wih0,
    const float* __restrict__ w1, const float* __restrict__ w2,
    const float* __restrict__ whh0, const float* __restrict__ wih1,
    const float* __restrict__ whh1, const float* __restrict__ hid,
    h16* __restrict__ E, h16* __restrict__ A, h16* __restrict__ B1,
    h16* __restrict__ B2, h16* __restrict__ D0, h16* __restrict__ D1,
    h16* __restrict__ D2, h16* __restrict__ HD)
{
  int i = blockIdx.x * 256 + threadIdx.x;
  const float* s; h16* d; int o;
  if      (i < Q_EMB)  { s = emb;  d = E;  o = i; }
  else if (i < Q_WIH0) { s = wih0; d = A;  o = i - Q_EMB; }
  else if (i < Q_W1)   { s = w1;   d = B1; o = i - Q_WIH0; }
  else if (i < Q_W2)   { s = w2;   d = B2; o = i - Q_W1; }
  else if (i < Q_WHH0) { s = whh0; d = D0; o = i - Q_W2; }
  else if (i < Q_WIH1) { s = wih1; d = D1; o = i - Q_WHH0; }
  else if (i < Q_WHH1) { s = whh1; d = D2; o = i - Q_WIH1; }
  else                 { s = hid;  d = HD; o = i - Q_WHH1; }
  float4 v = *(const float4*)(s + (size_t)o * 4);
  h16x4 ov = { (h16)v.x, (h16)v.y, (h16)v.z, (h16)v.w };
  *(h16x4*)(d + (size_t)o * 4) = ov;
}

// ---------- embedding gather -> fp16 X, time-major rows t = s*Bn + b ----------
__global__ void embed_k(const int* __restrict__ trg, const float* __restrict__ emb,
                        h16* __restrict__ Xh) {
  int t = blockIdx.x;
  int s = t >> 4, b = t & 15;
  int tok = trg[b * Sn + s];
  const float* src = emb + (size_t)tok * En;
  int e = threadIdx.x * 4;
  float4 v = *(const float4*)(src + e);
  h16x4 o = { (h16)v.x, (h16)v.y, (h16)v.z, (h16)v.w };
  *(h16x4*)(Xh + (size_t)t * En + e) = o;
}

// ---------- fp16 MFMA GEMM 128x128: C(M,N) = A(M,K) @ B(N,K)^T + bias ----------
template<int OUT_MODE, bool RELU, bool SWZ>
__global__ __launch_bounds__(256) void gemm_bt(
    const h16* __restrict__ A, const h16* __restrict__ B,
    const float* __restrict__ bias, void* __restrict__ C,
    int M, int N, int K)
{
  __shared__ h16 As[128 * 64];
  __shared__ h16 Bs[128 * 64];
  int tid = threadIdx.x;
  int l = tid & 63, wv = tid >> 6;
  int wr = wv >> 1, wc = wv & 1;

  int work = blockIdx.x;
  if (SWZ) { int q = gridDim.x >> 3; work = (work & 7) * q + (work >> 3); }
  int nMp = M >> 7;
  int brow = (work % nMp) << 7;
  int bcol = (work / nMp) << 7;

  f32x4 acc[4][4];
#pragma unroll
  for (int m = 0; m < 4; ++m)
#pragma unroll
    for (int n = 0; n < 4; ++n) acc[m][n] = (f32x4){0.f, 0.f, 0.f, 0.f};

  int nkt = K >> 6;
  for (int kt = 0; kt < nkt; ++kt) {
    const h16* Ag = A + (size_t)brow * K + kt * 64;
    const h16* Bg = B + (size_t)bcol * K + kt * 64;
#pragma unroll
    for (int c = tid; c < 2048; c += 256) {
      int half = c >> 10;
      int cc = c & 1023;
      int row = cc >> 3, slot = cc & 7;
      const h16* src = (half ? Bg : Ag) + (size_t)row * K + slot * 8;
      uint4 v = *(const uint4*)src;
      h16* dst = (half ? Bs : As) + row * 64 + ((slot ^ (row & 7)) << 3);
      *(uint4*)dst = v;
    }
    __syncthreads();
#pragma unroll
    for (int kk = 0; kk < 2; ++kk) {
      h16x8 af[4], bfr[4];
      int rb = wr * 64 + (l & 15);
      int cb2 = wc * 64 + (l & 15);
      int slot = kk * 4 + (l >> 4);
#pragma unroll
      for (int m = 0; m < 4; ++m) {
        int r = rb + m * 16;
        af[m] = *(const h16x8*)&As[r * 64 + ((slot ^ (r & 7)) << 3)];
      }
#pragma unroll
      for (int n = 0; n < 4; ++n) {
        int r = cb2 + n * 16;
        bfr[n] = *(const h16x8*)&Bs[r * 64 + ((slot ^ (r & 7)) << 3)];
      }
#pragma unroll
      for (int m = 0; m < 4; ++m)
#pragma unroll
        for (int n = 0; n < 4; ++n)
          acc[m][n] = __builtin_amdgcn_mfma_f32_16x16x32_f16(af[m], bfr[n], acc[m][n], 0, 0, 0);
    }
    __syncthreads();
  }

#pragma unroll
  for (int m = 0; m < 4; ++m) {
    int row0 = brow + wr * 64 + m * 16 + ((l >> 4) << 2);
#pragma unroll
    for (int n = 0; n < 4; ++n) {
      int col = bcol + wc * 64 + n * 16 + (l & 15);
      float bv = bias ? bias[col] : 0.f;
#pragma unroll
      for (int i = 0; i < 4; ++i) {
        int row = row0 + i;
        float v = acc[m][n][i] + bv;
        if (RELU) v = fmaxf(v, 0.f);
        if (OUT_MODE == 1) {
          ((h16*)C)[(size_t)row * N + col] = (h16)v;
        } else if (OUT_MODE == 2) {
          int rr = ((row & 15) << 7) + (row >> 4);
          ((float*)C)[(size_t)rr * N + col] = v;
        } else {
          ((float*)C)[(size_t)row * N + col] = v;
        }
      }
    }
  }
}

// ---------- fp16 MFMA GEMM 128Mx256N for the logit projection ----------
__global__ __launch_bounds__(256, 1) void gemm_bt256(
    const h16* __restrict__ A, const h16* __restrict__ B,
    const float* __restrict__ bias, float* __restrict__ C,
    int M, int N, int K)
{
  __shared__ h16 As[128 * 64];
  __shared__ h16 Bs[256 * 64];
  int tid = threadIdx.x;
  int l = tid & 63, wv = tid >> 6;
  int wr = wv >> 1, wc = wv & 1;

  int work = blockIdx.x;
  int q = gridDim.x >> 3; work = (work & 7) * q + (work >> 3);
  int nMp = M >> 7;
  int brow = (work % nMp) << 7;
  int bcol = (work / nMp) << 8;

  f32x4 acc[4][8];
#pragma unroll
  for (int m = 0; m < 4; ++m)
#pragma unroll
    for (int n = 0; n < 8; ++n) acc[m][n] = (f32x4){0.f, 0.f, 0.f, 0.f};

  int nkt = K >> 6;
  for (int kt = 0; kt < nkt; ++kt) {
    const h16* Ag = A + (size_t)brow * K + kt * 64;
    const h16* Bg = B + (size_t)bcol * K + kt * 64;
#pragma unroll
    for (int c = tid; c < 3072; c += 256) {
      int isB = (c >= 1024);
      int cc = isB ? (c - 1024) : c;
      int row = cc >> 3, slot = cc & 7;
      const h16* src = (isB ? Bg : Ag) + (size_t)row * K + slot * 8;
      uint4 v = *(const uint4*)src;
      h16* dst = (isB ? Bs : As) + row * 64 + ((slot ^ (row & 7)) << 3);
      *(uint4*)dst = v;
    }
    __syncthreads();
#pragma unroll
    for (int kk = 0; kk < 2; ++kk) {
      h16x8 af[4], bfr[8];
      int rb = wr * 64 + (l & 15);
      int cb2 = wc * 128 + (l & 15);
      int slot = kk * 4 + (l >> 4);
#pragma unroll
      for (int m = 0; m < 4; ++m) {
        int r = rb + m * 16;
        af[m] = *(const h16x8*)&As[r * 64 + ((slot ^ (r & 7)) << 3)];
      }
#pragma unroll
      for (int n = 0; n < 8; ++n) {
        int r = cb2 + n * 16;
        bfr[n] = *(const h16x8*)&Bs[r * 64 + ((slot ^ (r & 7)) << 3)];
      }
#pragma unroll
      for (int m = 0; m < 4; ++m)
#pragma unroll
        for (int n = 0; n < 8; ++n)
          acc[m][n] = __builtin_amdgcn_mfma_f32_16x16x32_f16(af[m], bfr[n], acc[m][n], 0, 0, 0);
    }
    __syncthreads();
  }

#pragma unroll
  for (int m = 0; m < 4; ++m) {
    int row0 = brow + wr * 64 + m * 16 + ((l >> 4) << 2);
#pragma unroll
    for (int n = 0; n < 8; ++n) {
      int col = bcol + wc * 128 + n * 16 + (l & 15);
      float bv = bias[col];
#pragma unroll
      for (int i = 0; i < 4; ++i) {
        int row = row0 + i;
        int rr = ((row & 15) << 7) + (row >> 4);   // b*128 + s
        C[(size_t)rr * N + col] = acc[m][n][i] + bv;
      }
    }
  }
}

// ---------- store-only grid barrier: no RMW, no root hop ----------
// Each block publishes flags[bid*32] = target (own 128B line, relaxed agent store).
// Wave 0 of EVERY block polls all 256 flags (4 lines/lane); divergent loop narrows
// as flags land. Entry __syncthreads drains prior vmem (ring stores) to coherence.
__device__ __forceinline__ void gbar2(int* __restrict__ flags, int target, int bid) {
  __syncthreads();
  int tid = threadIdx.x;
  if (tid == 0)
    __hip_atomic_store(&flags[bid << 5], target, __ATOMIC_RELAXED, __HIP_MEMORY_SCOPE_AGENT);
  if (tid < 64) {
    int q = tid << 2;
    for (;;) {
      int m0 = __hip_atomic_load(&flags[(q + 0) << 5], __ATOMIC_RELAXED, __HIP_MEMORY_SCOPE_AGENT);
      int m1 = __hip_atomic_load(&flags[(q + 1) << 5], __ATOMIC_RELAXED, __HIP_MEMORY_SCOPE_AGENT);
      int m2 = __hip_atomic_load(&flags[(q + 2) << 5], __ATOMIC_RELAXED, __HIP_MEMORY_SCOPE_AGENT);
      int m3 = __hip_atomic_load(&flags[(q + 3) << 5], __ATOMIC_RELAXED, __HIP_MEMORY_SCOPE_AGENT);
      if (m0 >= target && m1 >= target && m2 >= target && m3 >= target) break;
      __builtin_amdgcn_s_sleep(1);
    }
    asm volatile("" ::: "memory");
  }
  __syncthreads();
}

// ---------- persistent GRU recurrence ----------
// 256 blocks x 768 threads (12 waves), 1 block/CU. Block owns 4 columns of BOTH layers.
// Wave (c*3+role): role 0 = L0 hh-dots + L0 update; 1 = L1 ih-dots; 2 = L1 hh-dots + L1 update.
// fp32 running state in registers; cross-step fp16 state via per-step ring buffers:
// relaxed agent u16 stores from update lanes, plain vectorized reads of fresh addresses.
__global__ __launch_bounds__(768, 1) void gru_persist3(
    const float* __restrict__ gi0,
    const float* __restrict__ hidden,
    const h16* __restrict__ hinit16,
    const h16* __restrict__ whh0, const float* __restrict__ bhh0,
    const h16* __restrict__ wih1, const float* __restrict__ bih1,
    const h16* __restrict__ whh1, const float* __restrict__ bhh1,
    h16* __restrict__ h0ring,       // [128][16][1024]
    h16* __restrict__ H1A,          // [128][16][1024]
    int* __restrict__ flags)
{
  extern __shared__ h16 ldsw[];                     // 36 rows x 1024 h16 = 72KB weights
  __shared__ float cmb[4][3][16];                   // L1 ih partials

  int bid = blockIdx.x;
  int tid = threadIdx.x;
  int base = bid << 2;

  // one-time replay-staleness guard (local cache invalidate), before any ring reads
  __threadfence();

  // load this block's weight slice: rows r = c*9+g, g: 0-2 whh0, 3-5 wih1, 6-8 whh1
  for (int i = tid; i < 4608; i += 768) {
    int r = i >> 7, ch = i & 127;
    int c = r / 9, g = r % 9;
    const h16* src = (g < 3) ? whh0 + (((size_t)(g * 1024 + base + c)) << 10)
                   : (g < 6) ? wih1 + (((size_t)((g - 3) * 1024 + base + c)) << 10)
                             : whh1 + (((size_t)((g - 6) * 1024 + base + c)) << 10);
    *(uint4*)(ldsw + r * 1024 + ch * 8) = *(const uint4*)(src + ch * 8);
  }

  int wv = tid >> 6;                 // 0..11
  int l = tid & 63;
  int c = wv / 3, role = wv % 3;
  int j = base + c;
  int b = l >> 2, p = l & 3;
  const h16* wR = ldsw + (c * 9 + role * 3) * 1024;

  float bA = 0, bB = 0, bC = 0, bD = 0, bE = 0, bF = 0;
  if (role == 0) { bA = bhh0[j]; bB = bhh0[1024 + j]; bC = bhh0[2048 + j]; }
  if (role == 2) { bA = bih1[j]; bB = bih1[1024 + j]; bC = bih1[2048 + j];
                   bD = bhh1[j]; bE = bhh1[1024 + j]; bF = bhh1[2048 + j]; }
  float hprev = (role == 0) ? hidden[(b << 10) + j]
              : (role == 2) ? hidden[16384 + (b << 10) + j] : 0.f;
  __syncthreads();

  for (int s = 0; s <= Sn; ++s) {
    bool active = (role == 0) ? (s < Sn) : (s >= 1);
    // prefetch gi0 for this step's L0 update (latency hides under dots)
    float giR = 0.f, giZ = 0.f, giN = 0.f;
    if (role == 0 && p == 0 && s < Sn) {
      const float* gi = gi0 + (size_t)((s << 4) + b) * H3;
      giR = gi[j]; giZ = gi[1024 + j]; giN = gi[2048 + j];
    }
    float a0 = 0.f, a1 = 0.f, a2 = 0.f;
    if (active) {
      const h16* hrow = (role <= 1)
          ? ((s == 0) ? hinit16 : h0ring + (((size_t)(s - 1)) << 14))       // h0[s-1]
          : ((s <= 1) ? hinit16 + 16384 : H1A + (((size_t)(s - 2)) << 14)); // h1[s-2]
      const h16* hb = hrow + (b << 10);
#pragma unroll 8
      for (int t = 0; t < 32; ++t) {
        int k = (p << 3) + (t << 5);
        h16x8 h8 = *(const h16x8*)(hb + k);
        a0 = dot8(h8, *(const h16x8*)(wR + k), a0);
        a1 = dot8(h8, *(const h16x8*)(wR + 1024 + k), a1);
        a2 = dot8(h8, *(const h16x8*)(wR + 2048 + k), a2);
      }
      a0 += __shfl_xor(a0, 1, 64); a0 += __shfl_xor(a0, 2, 64);
      a1 += __shfl_xor(a1, 1, 64); a1 += __shfl_xor(a1, 2, 64);
      a2 += __shfl_xor(a2, 1, 64); a2 += __shfl_xor(a2, 2, 64);
      if (role == 1 && p == 0) { cmb[c][0][b] = a0; cmb[c][1][b] = a1; cmb[c][2][b] = a2; }
    }
    __syncthreads();   // [A] L1 ih partials visible
    if (active && p == 0) {
      if (role == 0) {
        float r = 1.f / (1.f + expf(-(giR + a0 + bA)));
        float z = 1.f / (1.f + expf(-(giZ + a1 + bB)));
        float n = tanhf(giN + r * (a2 + bC));
        float out = (1.f - z) * n + z * hprev;
        hprev = out;
        h16 hv = (h16)out; unsigned short us; __builtin_memcpy(&us, &hv, 2);
        __hip_atomic_store((unsigned short*)h0ring + (((size_t)s) << 14) + (b << 10) + j,
                           us, __ATOMIC_RELAXED, __HIP_MEMORY_SCOPE_AGENT);
      } else if (role == 2) {
        float air = cmb[c][0][b], aiz = cmb[c][1][b], ain = cmb[c][2][b];
        float r = 1.f / (1.f + expf(-(air + bA + a0 + bD)));
        float z = 1.f / (1.f + expf(-(aiz + bB + a1 + bE)));
        float n = tanhf(ain + bC + r * (a2 + bF));
        float out = (1.f - z) * n + z * hprev;
        hprev = out;
        h16 hv = (h16)out; unsigned short us; __builtin_memcpy(&us, &hv, 2);
        __hip_atomic_store((unsigned short*)H1A + (((size_t)(s - 1)) << 14) + (b << 10) + j,
                           us, __ATOMIC_RELAXED, __HIP_MEMORY_SCOPE_AGENT);
      }
    }
    if (s < Sn) gbar2(flags, s + 1, bid);
  }
}

extern "C" void kernel_launch(void* const* d_in, const int* in_sizes, int n_in,
                              void* d_out, int out_size, void* d_ws, size_t ws_size,
                              hipStream_t stream) {
  const float* hidden = (const float*)d_in[0];
  const int*   trg    = (const int*)d_in[1];
  const float* emb    = (const float*)d_in[2];
  const float* w_ih0  = (const float*)d_in[3];
  const float* w_hh0  = (const float*)d_in[4];
  const float* b_ih0  = (const float*)d_in[5];
  const float* b_hh0  = (const float*)d_in[6];
  const float* w_ih1  = (const float*)d_in[7];
  const float* w_hh1  = (const float*)d_in[8];
  const float* b_ih1  = (const float*)d_in[9];
  const float* b_hh1  = (const float*)d_in[10];
  const float* w1     = (const float*)d_in[11];
  const float* b1     = (const float*)d_in[12];
  const float* w2     = (const float*)d_in[13];
  const float* b2     = (const float*)d_in[14];
  const float* b_gen  = (const float*)d_in[15];

  char* ws = (char*)d_ws;
  size_t off = 0;
  float* GI0    = (float*)(ws + off); off += (size_t)Sn * Bn * H3 * 4;      // 25.2 MB
  h16* Xh       = (h16*)(ws + off);   off += (size_t)Sn * Bn * En * 2;
  h16* embH     = (h16*)(ws + off);   off += (size_t)Vn * En * 2;
  h16* wih0H    = (h16*)(ws + off);   off += (size_t)H3 * En * 2;
  h16* w1H      = (h16*)(ws + off);   off += (size_t)Hn * Hn * 2;
  h16* w2H      = (h16*)(ws + off);   off += (size_t)En * Hn * 2;
  h16* whh0H    = (h16*)(ws + off);   off += (size_t)H3 * Hn * 2;
  h16* wih1H    = (h16*)(ws + off);   off += (size_t)H3 * Hn * 2;
  h16* whh1H    = (h16*)(ws + off);   off += (size_t)H3 * Hn * 2;
  h16* H1A      = (h16*)(ws + off);   off += (size_t)Sn * Bn * Hn * 2;      // 4.2 MB
  h16* h0ring   = (h16*)(ws + off);   off += (size_t)Sn * Bn * Hn * 2;      // 4.2 MB
  h16* hinit16  = (h16*)(ws + off);   off += (size_t)2 * Bn * Hn * 2;
  int* flags    = (int*)(ws + off);   off += 32768;
  // Tb/Ub alias GI0 (dead after the recurrence)
  h16* Tb = (h16*)GI0;
  h16* Ub = (h16*)((char*)GI0 + (8u << 20));

  // fp16 copies of all operands (one fused launch) + embedding gather
  cvt_all_k<<<28320, 256, 0, stream>>>(emb, w_ih0, w1, w2, w_hh0, w_ih1, w_hh1, hidden,
                                       embH, wih0H, w1H, w2H, whh0H, wih1H, whh1H, hinit16);
  embed_k<<<Sn * Bn, 128, 0, stream>>>(trg, emb, Xh);

  // GI0 = X @ w_ih0^T + b_ih0 (hoisted out of the recurrence)
  gemm_bt<0, false, true><<<384, 256, 0, stream>>>(Xh, wih0H, b_ih0, GI0, Sn * Bn, H3, En);

  // persistent recurrence: 256 blocks (1/CU), store-only barrier per step
  (void)hipMemsetAsync(flags, 0, 32768, stream);
  const int LDSZ = 36 * 1024 * 2;   // 72KB dynamic
  (void)hipFuncSetAttribute(reinterpret_cast<const void*>(gru_persist3),
                            hipFuncAttributeMaxDynamicSharedMemorySize, LDSZ);
  gru_persist3<<<256, 768, LDSZ, stream>>>(GI0, hidden, hinit16,
                                           whh0H, b_hh0, wih1H, b_ih1, whh1H, b_hh1,
                                           h0ring, H1A, flags);

  // output head, batched over all 2048 rows
  gemm_bt<1, true,  true><<<128,  256, 0, stream>>>(H1A, w1H, b1, Tb, Sn * Bn, Hn, Hn);
  gemm_bt<1, false, true><<<64,   256, 0, stream>>>(Tb, w2H, b2, Ub, Sn * Bn, En, Hn);
  gemm_bt256<<<2000, 256, 0, stream>>>(Ub, embH, b_gen, (float*)d_out, Sn * Bn, Vn, En);
}